// Round 9
// baseline (194.686 us; speedup 1.0000x reference)
//
#include <hip/hip_runtime.h>

#define B_  2
#define T_  2048
#define C_  1024
#define H_  16
#define D_  64
#define M_  (B_*T_)   // 4096
#define N1_ (3*C_)    // 3072

typedef short bf16x8 __attribute__((ext_vector_type(8)));
typedef short bf16x4 __attribute__((ext_vector_type(4)));
typedef float f32x4 __attribute__((ext_vector_type(4)));
typedef unsigned short u16;
typedef u16 u16x8 __attribute__((ext_vector_type(8)));

#define QSCALE 0.18033688011112042f   // (1/8) * log2(e)
#define C8     11.541560327111707f    // 8 * log2(e)

__device__ __forceinline__ u16 f2bf(float f) {
  unsigned u = __float_as_uint(f);
  u += 0x7FFFu + ((u >> 16) & 1u);
  return (u16)(u >> 16);
}

__device__ __forceinline__ void gload16(const void* g, void* l) {
  __builtin_amdgcn_global_load_lds((__attribute__((address_space(1))) void*)g,
                                   (__attribute__((address_space(3))) void*)l,
                                   16, 0, 0);
}

// ---------------- fp32 -> bf16 conversion ----------------
__global__ __launch_bounds__(256) void cvt_bf16(const float* __restrict__ in,
                                                u16* __restrict__ out, int n) {
  int i = (blockIdx.x * 256 + threadIdx.x) * 8;
  if (i >= n) return;
  float4 a = *(const float4*)(in + i);
  float4 b = *(const float4*)(in + i + 4);
  u16x8 o;
  o[0] = f2bf(a.x); o[1] = f2bf(a.y); o[2] = f2bf(a.z); o[3] = f2bf(a.w);
  o[4] = f2bf(b.x); o[5] = f2bf(b.y); o[6] = f2bf(b.z); o[7] = f2bf(b.w);
  *(u16x8*)(out + i) = o;
}

// ---------------- shared GEMM mainloop: C += A[M,K] * W[N,K]^T ----------------
__device__ __forceinline__ void gemm_core(const u16* __restrict__ A,
                                          const u16* __restrict__ W,
                                          u16* As, u16* Bs,
                                          f32x4 (&acc)[4][4],
                                          int m0, int n0, int K) {
  int tid = threadIdx.x;
  int lane = tid & 63, wid = tid >> 6;
  int wr = wid >> 1, wc = wid & 1;

  int arow = wid * 16 + (lane >> 2);
  int ag = lane & 3;
  int sg = ag ^ ((arow >> 1) & 3);
  const u16* aSrc0 = A + (m0 + arow) * K + sg * 8;
  const u16* aSrc1 = aSrc0 + 64 * K;
  const u16* bSrc0 = W + (n0 + arow) * K + sg * 8;
  const u16* bSrc1 = bSrc0 + 64 * K;
  u16* aDst0 = As + (wid * 16) * 32;
  u16* aDst1 = As + (64 + wid * 16) * 32;
  u16* bDst0 = Bs + (wid * 16) * 32;
  u16* bDst1 = Bs + (64 + wid * 16) * 32;

  int rg = lane >> 4;
  int aoff[4], boff[4];
#pragma unroll
  for (int m = 0; m < 4; ++m) {
    int row = wr * 64 + m * 16 + (lane & 15);
    aoff[m] = row * 32 + (rg ^ ((row >> 1) & 3)) * 8;
    row = wc * 64 + m * 16 + (lane & 15);
    boff[m] = row * 32 + (rg ^ ((row >> 1) & 3)) * 8;
  }

  for (int kt = 0; kt < K / 32; ++kt) {
    int k0 = kt * 32;
    __syncthreads();
    gload16(aSrc0 + k0, aDst0);
    gload16(aSrc1 + k0, aDst1);
    gload16(bSrc0 + k0, bDst0);
    gload16(bSrc1 + k0, bDst1);
    __syncthreads();

    bf16x8 af[4], bfr[4];
#pragma unroll
    for (int m = 0; m < 4; ++m) af[m] = *(const bf16x8*)(As + aoff[m]);
#pragma unroll
    for (int n = 0; n < 4; ++n) bfr[n] = *(const bf16x8*)(Bs + boff[n]);
#pragma unroll
    for (int m = 0; m < 4; ++m)
#pragma unroll
      for (int n = 0; n < 4; ++n)
        acc[m][n] = __builtin_amdgcn_mfma_f32_16x16x32_bf16(af[m], bfr[n], acc[m][n], 0, 0, 0);
  }
}

// ---------------- GEMM1: qkv = x @ W_attn^T + b; Q pre-scaled by log2e/8 ----------------
__global__ __launch_bounds__(256) void gemm_qkv(const u16* __restrict__ A,
                                                const u16* __restrict__ W,
                                                const float* __restrict__ bias,
                                                u16* __restrict__ Qb,
                                                u16* __restrict__ Kb,
                                                u16* __restrict__ Vt) {
  __shared__ __align__(16) u16 As[128 * 32];
  __shared__ __align__(16) u16 Bs[128 * 32];
  f32x4 acc[4][4] = {};
  int m0 = blockIdx.x * 128, n0 = blockIdx.y * 128;
  gemm_core(A, W, As, Bs, acc, m0, n0, C_);

  int lane = threadIdx.x & 63, wid = threadIdx.x >> 6;
  int wr = wid >> 1, wc = wid & 1;
  int rg = lane >> 4, cl = lane & 15;
#pragma unroll
  for (int n = 0; n < 4; ++n) {
    int gn = n0 + wc * 64 + n * 16 + cl;
    float bv = bias[gn];
    int seg = gn >> 10, cc = gn & 1023;
    int h = cc >> 6, d = cc & 63;
    float sc = (seg == 0) ? QSCALE : 1.0f;
#pragma unroll
    for (int m = 0; m < 4; ++m) {
#pragma unroll
      for (int r = 0; r < 4; ++r) {
        int gm = m0 + wr * 64 + m * 16 + rg * 4 + r;
        int b = gm >> 11, t = gm & 2047;
        u16 val = f2bf((acc[m][n][r] + bv) * sc);
        int bh = b * 16 + h;
        if (seg == 0)      Qb[(bh * 2048 + t) * 64 + d] = val;
        else if (seg == 1) Kb[(bh * 2048 + t) * 64 + d] = val;
        else               Vt[(bh * 64 + d) * 2048 + t] = val;
      }
    }
  }
}

// ---------------- GEMM2: out = y @ W_proj^T + b (fp32 out) ----------------
__global__ __launch_bounds__(256) void gemm_proj(const u16* __restrict__ A,
                                                 const u16* __restrict__ W,
                                                 const float* __restrict__ bias,
                                                 float* __restrict__ out) {
  __shared__ __align__(16) u16 As[128 * 32];
  __shared__ __align__(16) u16 Bs[128 * 32];
  f32x4 acc[4][4] = {};
  int m0 = blockIdx.x * 128, n0 = blockIdx.y * 128;
  gemm_core(A, W, As, Bs, acc, m0, n0, C_);

  int lane = threadIdx.x & 63, wid = threadIdx.x >> 6;
  int wr = wid >> 1, wc = wid & 1;
  int rg = lane >> 4, cl = lane & 15;
#pragma unroll
  for (int n = 0; n < 4; ++n) {
    int gn = n0 + wc * 64 + n * 16 + cl;
    float bv = bias[gn];
#pragma unroll
    for (int m = 0; m < 4; ++m) {
#pragma unroll
      for (int r = 0; r < 4; ++r) {
        int gm = m0 + wr * 64 + m * 16 + rg * 4 + r;
        out[gm * 1024 + gn] = acc[m][n][r] + bv;
      }
    }
  }
}

// ---------------- flash attention v9: 16-q-row units, 4096 blocks, CU-local head ----
// bh = bid&31: CU c receives blocks c+256k, all with bh = c&31 -> one head's
// K/V per CU (512 KB, L2-resident; round-4's accidental locality, now on
// purpose). qb = 127-(bid>>5): per-CU qb spaced by 8 -> balanced. 16 blocks
// per CU at VGPR ~112 -> 4 waves/SIMD resident (round-4 limiter was 8
// blocks/CU, not VGPR). Body = round 5's proven kernel (no queue).
__global__ __launch_bounds__(64, 2) void attn_fwd(const u16* __restrict__ Qb,
                                                  const u16* __restrict__ Kb,
                                                  const u16* __restrict__ Vt,
                                                  u16* __restrict__ Yb) {
  __shared__ __align__(16) u16 Ps[16 * 64];
  int lane = threadIdx.x & 63;
  int cl = lane & 15, kg = lane >> 4;
  int bid = blockIdx.x;
  int bh = bid & 31;                   // fixed per CU (256 % 32 == 0)
  int qb = 127 - (bid >> 5);           // heavy-first, per-CU spacing 8
  int qw0 = qb * 16;
  int jmax = qb >> 2;
  const u16* Qp = Qb + (size_t)bh * (2048 * 64);
  const u16* Kp = Kb + (size_t)bh * (2048 * 64);
  const u16* Vp = Vt + (size_t)bh * (64 * 2048);

  int kbase = cl * 64 + kg * 8;        // K frag: + fc*1024 + j*4096
  int vbase = cl * 2048 + kg * 8;      // V frag: + dc*32768 + j*64

  // Q frags (B-operand): q = qw0 + cl, d-slice dk*32 + kg*8
  bf16x8 qf[2];
#pragma unroll
  for (int dk = 0; dk < 2; ++dk)
    qf[dk] = *(const bf16x8*)(Qp + (qw0 + cl) * 64 + dk * 32 + kg * 8);

  f32x4 o[4] = {};
  float lsum = 0.f;

  auto LOADK = [&](bf16x8 (&kf)[4][2], int j) {
    const u16* Kj = Kp + j * 4096 + kbase;
#pragma unroll
    for (int fc = 0; fc < 4; ++fc) {
      kf[fc][0] = *(const bf16x8*)(Kj + fc * 1024);
      kf[fc][1] = *(const bf16x8*)(Kj + fc * 1024 + 32);
    }
  };

  auto FULL = [&](bf16x8 (&kf)[4][2], int j) {
    bf16x8 vf[4][2];
    const u16* Vj = Vp + j * 64 + vbase;
#pragma unroll
    for (int dc = 0; dc < 4; ++dc) {
      vf[dc][0] = *(const bf16x8*)(Vj + dc * 32768);
      vf[dc][1] = *(const bf16x8*)(Vj + dc * 32768 + 32);
    }
    f32x4 s[4];
#pragma unroll
    for (int fc = 0; fc < 4; ++fc) {
      f32x4 z = {};
      z = __builtin_amdgcn_mfma_f32_16x16x32_bf16(kf[fc][0], qf[0], z, 0, 0, 0);
      z = __builtin_amdgcn_mfma_f32_16x16x32_bf16(kf[fc][1], qf[1], z, 0, 0, 0);
      s[fc] = z;
    }
    int rowb = cl * 64;
#pragma unroll
    for (int fc = 0; fc < 4; ++fc) {
      bf16x4 pw;
#pragma unroll
      for (int r = 0; r < 4; ++r) {
        float p = exp2f(s[fc][r] - C8);
        lsum += p;
        pw[r] = (short)f2bf(p);
      }
      *(bf16x4*)(Ps + rowb + (((fc * 2 + (kg >> 1)) ^ (cl & 7)) * 8) + (kg & 1) * 4) = pw;
    }
    bf16x8 pf[2];
    pf[0] = *(const bf16x8*)(Ps + rowb + ((kg ^ (cl & 7)) * 8));
    pf[1] = *(const bf16x8*)(Ps + rowb + (((kg + 4) ^ (cl & 7)) * 8));
#pragma unroll
    for (int kv2 = 0; kv2 < 2; ++kv2)
#pragma unroll
      for (int dc = 0; dc < 4; ++dc)
        o[dc] = __builtin_amdgcn_mfma_f32_16x16x32_bf16(pf[kv2], vf[dc][kv2], o[dc], 0, 0, 0);
  };

  auto EDGE = [&](bf16x8 (&kf)[4][2], int j) {
    int fcTop = qb & 3;
    int kvTop = (qb & 3) >> 1;
    bf16x8 vf[4][2];
    const u16* Vj = Vp + j * 64 + vbase;
#pragma unroll
    for (int dc = 0; dc < 4; ++dc) {
      vf[dc][0] = *(const bf16x8*)(Vj + dc * 32768);
      if (kvTop) vf[dc][1] = *(const bf16x8*)(Vj + dc * 32768 + 32);
    }
    f32x4 s[4];
#pragma unroll
    for (int fc = 0; fc < 4; ++fc)
      if (fc <= fcTop) {
        f32x4 z = {};
        z = __builtin_amdgcn_mfma_f32_16x16x32_bf16(kf[fc][0], qf[0], z, 0, 0, 0);
        z = __builtin_amdgcn_mfma_f32_16x16x32_bf16(kf[fc][1], qf[1], z, 0, 0, 0);
        s[fc] = z;
      }
    int rowb = cl * 64;
    int qg = qw0 + cl;
#pragma unroll
    for (int fc = 0; fc < 4; ++fc) {
      bf16x4 pw;
      if (fc <= fcTop) {
#pragma unroll
        for (int r = 0; r < 4; ++r) {
          int kvg = j * 64 + fc * 16 + kg * 4 + r;
          float p = (kvg <= qg) ? exp2f(s[fc][r] - C8) : 0.f;
          lsum += p;
          pw[r] = (short)f2bf(p);
        }
      } else {
        pw[0] = 0; pw[1] = 0; pw[2] = 0; pw[3] = 0;
      }
      *(bf16x4*)(Ps + rowb + (((fc * 2 + (kg >> 1)) ^ (cl & 7)) * 8) + (kg & 1) * 4) = pw;
    }
    bf16x8 pf[2];
    pf[0] = *(const bf16x8*)(Ps + rowb + ((kg ^ (cl & 7)) * 8));
    if (kvTop) pf[1] = *(const bf16x8*)(Ps + rowb + (((kg + 4) ^ (cl & 7)) * 8));
#pragma unroll
    for (int kv2 = 0; kv2 < 2; ++kv2)
      if (kv2 <= kvTop) {
#pragma unroll
        for (int dc = 0; dc < 4; ++dc)
          o[dc] = __builtin_amdgcn_mfma_f32_16x16x32_bf16(pf[kv2], vf[dc][kv2], o[dc], 0, 0, 0);
      }
  };

  bf16x8 kA[4][2], kB[4][2];
  LOADK(kA, 0);
  if (jmax == 0) {
    EDGE(kA, 0);
  } else {
    LOADK(kB, 1);
    int j = 0;
    while (j + 1 < jmax) {
      FULL(kA, j);
      LOADK(kA, j + 2);
      FULL(kB, j + 1);
      LOADK(kB, (j + 3 <= jmax) ? j + 3 : jmax);
      j += 2;
    }
    if (j < jmax) { FULL(kA, j); EDGE(kB, jmax); }
    else          { EDGE(kA, jmax); }
  }

  // epilogue: reduce l across kg groups, normalize, store
  int b = bh >> 4, h = bh & 15;
  float l = lsum;
  l += __shfl_xor(l, 16);
  l += __shfl_xor(l, 32);
  float linv = 1.f / l;
  float li[4];
#pragma unroll
  for (int r = 0; r < 4; ++r) li[r] = __shfl(linv, kg * 4 + r);
#pragma unroll
  for (int dc = 0; dc < 4; ++dc)
#pragma unroll
    for (int r = 0; r < 4; ++r) {
      int t = qw0 + kg * 4 + r;
      int d = dc * 16 + cl;
      Yb[((size_t)(b * 2048 + t)) * 1024 + h * 64 + d] = f2bf(o[dc][r] * li[r]);
    }
}

extern "C" void kernel_launch(void* const* d_in, const int* in_sizes, int n_in,
                              void* d_out, int out_size, void* d_ws, size_t ws_size,
                              hipStream_t stream) {
  const float* x  = (const float*)d_in[0];
  const float* Wa = (const float*)d_in[1];
  const float* ba = (const float*)d_in[2];
  const float* Wp = (const float*)d_in[3];
  const float* bp = (const float*)d_in[4];
  float* out = (float*)d_out;

  u16* xb  = (u16*)d_ws;
  u16* Wab = xb  + (size_t)M_ * C_;
  u16* Wpb = Wab + (size_t)N1_ * C_;
  u16* Qb  = Wpb + (size_t)C_ * C_;
  u16* Kb  = Qb  + (size_t)M_ * C_;
  u16* Vt  = Kb  + (size_t)M_ * C_;
  u16* Yb  = Vt  + (size_t)M_ * C_;

  cvt_bf16<<<(M_ * C_) / 2048, 256, 0, stream>>>(x, xb, M_ * C_);
  cvt_bf16<<<(N1_ * C_) / 2048, 256, 0, stream>>>(Wa, Wab, N1_ * C_);
  cvt_bf16<<<(C_ * C_) / 2048, 256, 0, stream>>>(Wp, Wpb, C_ * C_);
  gemm_qkv<<<dim3(M_ / 128, N1_ / 128), 256, 0, stream>>>(xb, Wab, ba, Qb, Kb, Vt);
  attn_fwd<<<4096, 64, 0, stream>>>(Qb, Kb, Vt, Yb);
  gemm_proj<<<dim3(M_ / 128, C_ / 128), 256, 0, stream>>>(Yb, Wpb, bp, out);
}

// Round 10
// 173.143 us; speedup vs baseline: 1.1244x; 1.1244x over previous
//
#include <hip/hip_runtime.h>

#define B_  2
#define T_  2048
#define C_  1024
#define H_  16
#define D_  64
#define M_  (B_*T_)   // 4096
#define N1_ (3*C_)    // 3072

typedef short bf16x8 __attribute__((ext_vector_type(8)));
typedef short bf16x4 __attribute__((ext_vector_type(4)));
typedef float f32x4 __attribute__((ext_vector_type(4)));
typedef unsigned u32x4 __attribute__((ext_vector_type(4)));
typedef unsigned u32x2 __attribute__((ext_vector_type(2)));
typedef unsigned short u16;
typedef u16 u16x8 __attribute__((ext_vector_type(8)));

#define QSCALE 0.18033688011112042f   // (1/8) * log2(e)
#define C8     11.541560327111707f    // 8 * log2(e)

__device__ __forceinline__ u16 f2bf(float f) {
  unsigned u = __float_as_uint(f);
  u += 0x7FFFu + ((u >> 16) & 1u);
  return (u16)(u >> 16);
}

__device__ __forceinline__ unsigned cvtpk(float lo, float hi) {
  unsigned r;
  asm("v_cvt_pk_bf16_f32 %0, %1, %2" : "=v"(r) : "v"(lo), "v"(hi));
  return r;
}

__device__ __forceinline__ void pl32(unsigned &a, unsigned &b) {
#if __has_builtin(__builtin_amdgcn_permlane32_swap)
  u32x2 r = __builtin_amdgcn_permlane32_swap(a, b, false, false);
  a = r.x; b = r.y;
#else
  asm("v_permlane32_swap_b32 %0, %1" : "+v"(a), "+v"(b));
#endif
}

__device__ __forceinline__ void gload16(const void* g, void* l) {
  __builtin_amdgcn_global_load_lds((__attribute__((address_space(1))) void*)g,
                                   (__attribute__((address_space(3))) void*)l,
                                   16, 0, 0);
}

// ---------------- fp32 -> bf16 conversion ----------------
__global__ __launch_bounds__(256) void cvt_bf16(const float* __restrict__ in,
                                                u16* __restrict__ out, int n) {
  int i = (blockIdx.x * 256 + threadIdx.x) * 8;
  if (i >= n) return;
  float4 a = *(const float4*)(in + i);
  float4 b = *(const float4*)(in + i + 4);
  u16x8 o;
  o[0] = f2bf(a.x); o[1] = f2bf(a.y); o[2] = f2bf(a.z); o[3] = f2bf(a.w);
  o[4] = f2bf(b.x); o[5] = f2bf(b.y); o[6] = f2bf(b.z); o[7] = f2bf(b.w);
  *(u16x8*)(out + i) = o;
}

// ---------------- shared GEMM mainloop: C += A[M,K] * W[N,K]^T ----------------
__device__ __forceinline__ void gemm_core(const u16* __restrict__ A,
                                          const u16* __restrict__ W,
                                          u16* As, u16* Bs,
                                          f32x4 (&acc)[4][4],
                                          int m0, int n0, int K) {
  int tid = threadIdx.x;
  int lane = tid & 63, wid = tid >> 6;
  int wr = wid >> 1, wc = wid & 1;

  int arow = wid * 16 + (lane >> 2);
  int ag = lane & 3;
  int sg = ag ^ ((arow >> 1) & 3);
  const u16* aSrc0 = A + (m0 + arow) * K + sg * 8;
  const u16* aSrc1 = aSrc0 + 64 * K;
  const u16* bSrc0 = W + (n0 + arow) * K + sg * 8;
  const u16* bSrc1 = bSrc0 + 64 * K;
  u16* aDst0 = As + (wid * 16) * 32;
  u16* aDst1 = As + (64 + wid * 16) * 32;
  u16* bDst0 = Bs + (wid * 16) * 32;
  u16* bDst1 = Bs + (64 + wid * 16) * 32;

  int rg = lane >> 4;
  int aoff[4], boff[4];
#pragma unroll
  for (int m = 0; m < 4; ++m) {
    int row = wr * 64 + m * 16 + (lane & 15);
    aoff[m] = row * 32 + (rg ^ ((row >> 1) & 3)) * 8;
    row = wc * 64 + m * 16 + (lane & 15);
    boff[m] = row * 32 + (rg ^ ((row >> 1) & 3)) * 8;
  }

  for (int kt = 0; kt < K / 32; ++kt) {
    int k0 = kt * 32;
    __syncthreads();
    gload16(aSrc0 + k0, aDst0);
    gload16(aSrc1 + k0, aDst1);
    gload16(bSrc0 + k0, bDst0);
    gload16(bSrc1 + k0, bDst1);
    __syncthreads();

    bf16x8 af[4], bfr[4];
#pragma unroll
    for (int m = 0; m < 4; ++m) af[m] = *(const bf16x8*)(As + aoff[m]);
#pragma unroll
    for (int n = 0; n < 4; ++n) bfr[n] = *(const bf16x8*)(Bs + boff[n]);
#pragma unroll
    for (int m = 0; m < 4; ++m)
#pragma unroll
      for (int n = 0; n < 4; ++n)
        acc[m][n] = __builtin_amdgcn_mfma_f32_16x16x32_bf16(af[m], bfr[n], acc[m][n], 0, 0, 0);
  }
}

// ---------------- GEMM1: qkv = x @ W_attn^T + b; Q pre-scaled by log2e/8 ----------------
__global__ __launch_bounds__(256) void gemm_qkv(const u16* __restrict__ A,
                                                const u16* __restrict__ W,
                                                const float* __restrict__ bias,
                                                u16* __restrict__ Qb,
                                                u16* __restrict__ Kb,
                                                u16* __restrict__ Vt) {
  __shared__ __align__(16) u16 As[128 * 32];
  __shared__ __align__(16) u16 Bs[128 * 32];
  f32x4 acc[4][4] = {};
  int m0 = blockIdx.x * 128, n0 = blockIdx.y * 128;
  gemm_core(A, W, As, Bs, acc, m0, n0, C_);

  int lane = threadIdx.x & 63, wid = threadIdx.x >> 6;
  int wr = wid >> 1, wc = wid & 1;
  int rg = lane >> 4, cl = lane & 15;
#pragma unroll
  for (int n = 0; n < 4; ++n) {
    int gn = n0 + wc * 64 + n * 16 + cl;
    float bv = bias[gn];
    int seg = gn >> 10, cc = gn & 1023;
    int h = cc >> 6, d = cc & 63;
    float sc = (seg == 0) ? QSCALE : 1.0f;
#pragma unroll
    for (int m = 0; m < 4; ++m) {
#pragma unroll
      for (int r = 0; r < 4; ++r) {
        int gm = m0 + wr * 64 + m * 16 + rg * 4 + r;
        int b = gm >> 11, t = gm & 2047;
        u16 val = f2bf((acc[m][n][r] + bv) * sc);
        int bh = b * 16 + h;
        if (seg == 0)      Qb[(bh * 2048 + t) * 64 + d] = val;
        else if (seg == 1) Kb[(bh * 2048 + t) * 64 + d] = val;
        else               Vt[(bh * 64 + d) * 2048 + t] = val;
      }
    }
  }
}

// ---------------- GEMM2: out = y @ W_proj^T + b (fp32 out) ----------------
__global__ __launch_bounds__(256) void gemm_proj(const u16* __restrict__ A,
                                                 const u16* __restrict__ W,
                                                 const float* __restrict__ bias,
                                                 float* __restrict__ out) {
  __shared__ __align__(16) u16 As[128 * 32];
  __shared__ __align__(16) u16 Bs[128 * 32];
  f32x4 acc[4][4] = {};
  int m0 = blockIdx.x * 128, n0 = blockIdx.y * 128;
  gemm_core(A, W, As, Bs, acc, m0, n0, C_);

  int lane = threadIdx.x & 63, wid = threadIdx.x >> 6;
  int wr = wid >> 1, wc = wid & 1;
  int rg = lane >> 4, cl = lane & 15;
#pragma unroll
  for (int n = 0; n < 4; ++n) {
    int gn = n0 + wc * 64 + n * 16 + cl;
    float bv = bias[gn];
#pragma unroll
    for (int m = 0; m < 4; ++m) {
#pragma unroll
      for (int r = 0; r < 4; ++r) {
        int gm = m0 + wr * 64 + m * 16 + rg * 4 + r;
        out[gm * 1024 + gn] = acc[m][n][r] + bv;
      }
    }
  }
}

// ---------------- flash attention v10: R4 structure, in-register P (T12) ----------
// 2048 one-wave blocks, bh=bid&31 / qwi=63-(bid>>5) (R4's proven mapping).
// P path: C-init = -C8 (no subtract), v_cvt_pk_bf16_f32 pack, permlane32_swap
// across the kg-bit1 lane split; kg-bit0/word permutation folded into V's
// per-lane addresses (2x b64 loads at kvb and kvb+8). Zero LDS, zero barriers.
__global__ __launch_bounds__(64, 2) void attn_fwd(const u16* __restrict__ Qb,
                                                  const u16* __restrict__ Kb,
                                                  const u16* __restrict__ Vt,
                                                  u16* __restrict__ Yb) {
  int lane = threadIdx.x & 63;
  int cl = lane & 15, kg = lane >> 4;
  int bid = blockIdx.x;
  int bh = bid & 31;
  int qwi = 63 - (bid >> 5);
  int qw0 = qwi * 32;
  int jmax = qwi >> 1;
  const u16* Qp = Qb + (size_t)bh * (2048 * 64);
  const u16* Kp = Kb + (size_t)bh * (2048 * 64);
  const u16* Vp = Vt + (size_t)bh * (64 * 2048);

  int kbase = cl * 64 + kg * 8;                        // K frag addr
  int vbase = cl * 2048 + (kg >> 1) * 16 + (kg & 1) * 4; // V frag addr (permuted kv)

  // Q fragments (B-operand): q = qw0 + fr*16 + cl, d-slice dk*32 + kg*8
  bf16x8 qf[2][2];
#pragma unroll
  for (int fr = 0; fr < 2; ++fr)
#pragma unroll
    for (int dk = 0; dk < 2; ++dk)
      qf[fr][dk] = *(const bf16x8*)(Qp + (qw0 + fr * 16 + cl) * 64 + dk * 32 + kg * 8);

  f32x4 o[2][4] = {};
  float lsum[2] = {0.f, 0.f};
  const f32x4 CINIT = {-C8, -C8, -C8, -C8};

  auto LOADK = [&](bf16x8 (&kf)[4][2], int j) {
    const u16* Kj = Kp + j * 4096 + kbase;
#pragma unroll
    for (int fc = 0; fc < 4; ++fc) {
      kf[fc][0] = *(const bf16x8*)(Kj + fc * 1024);
      kf[fc][1] = *(const bf16x8*)(Kj + fc * 1024 + 32);
    }
  };

  auto CORE = [&](bf16x8 (&kf)[4][2], int j, bool edge) {
    // V frags (permuted-kv layout): 2x b64 per (dc,kv2), issue early
    bf16x4 va[4][2], vb[4][2];
    const u16* Vj = Vp + j * 64 + vbase;
#pragma unroll
    for (int dc = 0; dc < 4; ++dc)
#pragma unroll
      for (int kv2 = 0; kv2 < 2; ++kv2) {
        va[dc][kv2] = *(const bf16x4*)(Vj + dc * 32768 + kv2 * 32);
        vb[dc][kv2] = *(const bf16x4*)(Vj + dc * 32768 + kv2 * 32 + 8);
      }
    // S^T = K Q^T + (-C8): lane holds q = fr*16+cl, kv = fc*16 + kg*4 + r
    f32x4 s[2][4];
#pragma unroll
    for (int fc = 0; fc < 4; ++fc)
#pragma unroll
      for (int fr = 0; fr < 2; ++fr) {
        f32x4 z = CINIT;
        z = __builtin_amdgcn_mfma_f32_16x16x32_bf16(kf[fc][0], qf[fr][0], z, 0, 0, 0);
        z = __builtin_amdgcn_mfma_f32_16x16x32_bf16(kf[fc][1], qf[fr][1], z, 0, 0, 0);
        s[fr][fc] = z;
      }
    if (edge) {
#pragma unroll
      for (int fr = 0; fr < 2; ++fr) {
        int qg = qw0 + fr * 16 + cl;
#pragma unroll
        for (int fc = 0; fc < 4; ++fc)
#pragma unroll
          for (int r = 0; r < 4; ++r)
            if (j * 64 + fc * 16 + kg * 4 + r > qg) s[fr][fc][r] = -1e30f;
      }
    }
    // P = exp2(S); pack pairs; permlane32_swap; PV (no LDS)
#pragma unroll
    for (int fr = 0; fr < 2; ++fr) {
      unsigned W0[4], W1[4];
#pragma unroll
      for (int fc = 0; fc < 4; ++fc) {
        float p0 = exp2f(s[fr][fc][0]);
        float p1 = exp2f(s[fr][fc][1]);
        float p2 = exp2f(s[fr][fc][2]);
        float p3 = exp2f(s[fr][fc][3]);
        lsum[fr] += (p0 + p1) + (p2 + p3);
        W0[fc] = cvtpk(p0, p1);
        W1[fc] = cvtpk(p2, p3);
      }
      pl32(W0[0], W0[1]);
      pl32(W1[0], W1[1]);
      pl32(W0[2], W0[3]);
      pl32(W1[2], W1[3]);
#pragma unroll
      for (int kv2 = 0; kv2 < 2; ++kv2) {
        u32x4 pw = {W0[kv2 * 2], W1[kv2 * 2], W0[kv2 * 2 + 1], W1[kv2 * 2 + 1]};
        bf16x8 pf = __builtin_bit_cast(bf16x8, pw);
#pragma unroll
        for (int dc = 0; dc < 4; ++dc) {
          bf16x8 vf = __builtin_shufflevector(va[dc][kv2], vb[dc][kv2],
                                              0, 1, 2, 3, 4, 5, 6, 7);
          o[fr][dc] = __builtin_amdgcn_mfma_f32_16x16x32_bf16(pf, vf, o[fr][dc], 0, 0, 0);
        }
      }
    }
  };

  bf16x8 kA[4][2], kB[4][2];
  LOADK(kA, 0);
  if (jmax == 0) {
    CORE(kA, 0, true);
  } else {
    LOADK(kB, 1);
    int j = 0;
    while (j + 1 < jmax) {
      CORE(kA, j, false);
      LOADK(kA, j + 2);
      CORE(kB, j + 1, false);
      LOADK(kB, (j + 3 <= jmax) ? j + 3 : jmax);
      j += 2;
    }
    if (j < jmax) { CORE(kA, j, false); CORE(kB, jmax, true); }
    else          { CORE(kA, jmax, true); }
  }

  // epilogue: reduce l across kg lanes, normalize, store
  int b = bh >> 4, h = bh & 15;
#pragma unroll
  for (int fr = 0; fr < 2; ++fr) {
    float l = lsum[fr];
    l += __shfl_xor(l, 16);
    l += __shfl_xor(l, 32);
    float linv = 1.f / l;
    float li[4];
#pragma unroll
    for (int r = 0; r < 4; ++r) li[r] = __shfl(linv, kg * 4 + r);
#pragma unroll
    for (int dc = 0; dc < 4; ++dc)
#pragma unroll
      for (int r = 0; r < 4; ++r) {
        int t = qw0 + fr * 16 + kg * 4 + r;
        int d = dc * 16 + cl;
        Yb[((size_t)(b * 2048 + t)) * 1024 + h * 64 + d] = f2bf(o[fr][dc][r] * li[r]);
      }
  }
}

extern "C" void kernel_launch(void* const* d_in, const int* in_sizes, int n_in,
                              void* d_out, int out_size, void* d_ws, size_t ws_size,
                              hipStream_t stream) {
  const float* x  = (const float*)d_in[0];
  const float* Wa = (const float*)d_in[1];
  const float* ba = (const float*)d_in[2];
  const float* Wp = (const float*)d_in[3];
  const float* bp = (const float*)d_in[4];
  float* out = (float*)d_out;

  u16* xb  = (u16*)d_ws;
  u16* Wab = xb  + (size_t)M_ * C_;
  u16* Wpb = Wab + (size_t)N1_ * C_;
  u16* Qb  = Wpb + (size_t)C_ * C_;
  u16* Kb  = Qb  + (size_t)M_ * C_;
  u16* Vt  = Kb  + (size_t)M_ * C_;
  u16* Yb  = Vt  + (size_t)M_ * C_;

  cvt_bf16<<<(M_ * C_) / 2048, 256, 0, stream>>>(x, xb, M_ * C_);
  cvt_bf16<<<(N1_ * C_) / 2048, 256, 0, stream>>>(Wa, Wab, N1_ * C_);
  cvt_bf16<<<(C_ * C_) / 2048, 256, 0, stream>>>(Wp, Wpb, C_ * C_);
  gemm_qkv<<<dim3(M_ / 128, N1_ / 128), 256, 0, stream>>>(xb, Wab, ba, Qb, Kb, Vt);
  attn_fwd<<<2048, 64, 0, stream>>>(Qb, Kb, Vt, Yb);
  gemm_proj<<<dim3(M_ / 128, C_ / 128), 256, 0, stream>>>(Yb, Wpb, bp, out);
}

// Round 11
// 143.169 us; speedup vs baseline: 1.3598x; 1.2094x over previous
//
#include <hip/hip_runtime.h>

#define B_  2
#define T_  2048
#define C_  1024
#define H_  16
#define D_  64
#define M_  (B_*T_)   // 4096
#define N1_ (3*C_)    // 3072

typedef short bf16x8 __attribute__((ext_vector_type(8)));
typedef short bf16x4 __attribute__((ext_vector_type(4)));
typedef float f32x4 __attribute__((ext_vector_type(4)));
typedef unsigned short u16;
typedef u16 u16x8 __attribute__((ext_vector_type(8)));

#define QSCALE 0.18033688011112042f   // (1/8) * log2(e)
#define C8     11.541560327111707f    // 8 * log2(e)

__device__ __forceinline__ u16 f2bf(float f) {
  unsigned u = __float_as_uint(f);
  u += 0x7FFFu + ((u >> 16) & 1u);
  return (u16)(u >> 16);
}

__device__ __forceinline__ void gload16(const void* g, void* l) {
  __builtin_amdgcn_global_load_lds((__attribute__((address_space(1))) void*)g,
                                   (__attribute__((address_space(3))) void*)l,
                                   16, 0, 0);
}

// ---------------- fp32 -> bf16 conversion ----------------
__global__ __launch_bounds__(256) void cvt_bf16(const float* __restrict__ in,
                                                u16* __restrict__ out, int n) {
  int i = (blockIdx.x * 256 + threadIdx.x) * 8;
  if (i >= n) return;
  float4 a = *(const float4*)(in + i);
  float4 b = *(const float4*)(in + i + 4);
  u16x8 o;
  o[0] = f2bf(a.x); o[1] = f2bf(a.y); o[2] = f2bf(a.z); o[3] = f2bf(a.w);
  o[4] = f2bf(b.x); o[5] = f2bf(b.y); o[6] = f2bf(b.z); o[7] = f2bf(b.w);
  *(u16x8*)(out + i) = o;
}

// ---------------- shared GEMM mainloop: C += A[M,K] * W[N,K]^T ----------------
__device__ __forceinline__ void gemm_core(const u16* __restrict__ A,
                                          const u16* __restrict__ W,
                                          u16* As, u16* Bs,
                                          f32x4 (&acc)[4][4],
                                          int m0, int n0, int K) {
  int tid = threadIdx.x;
  int lane = tid & 63, wid = tid >> 6;
  int wr = wid >> 1, wc = wid & 1;

  int arow = wid * 16 + (lane >> 2);
  int ag = lane & 3;
  int sg = ag ^ ((arow >> 1) & 3);
  const u16* aSrc0 = A + (m0 + arow) * K + sg * 8;
  const u16* aSrc1 = aSrc0 + 64 * K;
  const u16* bSrc0 = W + (n0 + arow) * K + sg * 8;
  const u16* bSrc1 = bSrc0 + 64 * K;
  u16* aDst0 = As + (wid * 16) * 32;
  u16* aDst1 = As + (64 + wid * 16) * 32;
  u16* bDst0 = Bs + (wid * 16) * 32;
  u16* bDst1 = Bs + (64 + wid * 16) * 32;

  int rg = lane >> 4;
  int aoff[4], boff[4];
#pragma unroll
  for (int m = 0; m < 4; ++m) {
    int row = wr * 64 + m * 16 + (lane & 15);
    aoff[m] = row * 32 + (rg ^ ((row >> 1) & 3)) * 8;
    row = wc * 64 + m * 16 + (lane & 15);
    boff[m] = row * 32 + (rg ^ ((row >> 1) & 3)) * 8;
  }

  for (int kt = 0; kt < K / 32; ++kt) {
    int k0 = kt * 32;
    __syncthreads();
    gload16(aSrc0 + k0, aDst0);
    gload16(aSrc1 + k0, aDst1);
    gload16(bSrc0 + k0, bDst0);
    gload16(bSrc1 + k0, bDst1);
    __syncthreads();

    bf16x8 af[4], bfr[4];
#pragma unroll
    for (int m = 0; m < 4; ++m) af[m] = *(const bf16x8*)(As + aoff[m]);
#pragma unroll
    for (int n = 0; n < 4; ++n) bfr[n] = *(const bf16x8*)(Bs + boff[n]);
#pragma unroll
    for (int m = 0; m < 4; ++m)
#pragma unroll
      for (int n = 0; n < 4; ++n)
        acc[m][n] = __builtin_amdgcn_mfma_f32_16x16x32_bf16(af[m], bfr[n], acc[m][n], 0, 0, 0);
  }
}

// ---------------- GEMM1: qkv = x @ W_attn^T + b; Q pre-scaled by log2e/8 ----------------
__global__ __launch_bounds__(256) void gemm_qkv(const u16* __restrict__ A,
                                                const u16* __restrict__ W,
                                                const float* __restrict__ bias,
                                                u16* __restrict__ Qb,
                                                u16* __restrict__ Kb,
                                                u16* __restrict__ Vt) {
  __shared__ __align__(16) u16 As[128 * 32];
  __shared__ __align__(16) u16 Bs[128 * 32];
  f32x4 acc[4][4] = {};
  int m0 = blockIdx.x * 128, n0 = blockIdx.y * 128;
  gemm_core(A, W, As, Bs, acc, m0, n0, C_);

  int lane = threadIdx.x & 63, wid = threadIdx.x >> 6;
  int wr = wid >> 1, wc = wid & 1;
  int rg = lane >> 4, cl = lane & 15;
#pragma unroll
  for (int n = 0; n < 4; ++n) {
    int gn = n0 + wc * 64 + n * 16 + cl;
    float bv = bias[gn];
    int seg = gn >> 10, cc = gn & 1023;
    int h = cc >> 6, d = cc & 63;
    float sc = (seg == 0) ? QSCALE : 1.0f;
#pragma unroll
    for (int m = 0; m < 4; ++m) {
#pragma unroll
      for (int r = 0; r < 4; ++r) {
        int gm = m0 + wr * 64 + m * 16 + rg * 4 + r;
        int b = gm >> 11, t = gm & 2047;
        u16 val = f2bf((acc[m][n][r] + bv) * sc);
        int bh = b * 16 + h;
        if (seg == 0)      Qb[(bh * 2048 + t) * 64 + d] = val;
        else if (seg == 1) Kb[(bh * 2048 + t) * 64 + d] = val;
        else               Vt[(bh * 64 + d) * 2048 + t] = val;
      }
    }
  }
}

// ---------------- GEMM2: out = y @ W_proj^T + b (fp32 out) ----------------
__global__ __launch_bounds__(256) void gemm_proj(const u16* __restrict__ A,
                                                 const u16* __restrict__ W,
                                                 const float* __restrict__ bias,
                                                 float* __restrict__ out) {
  __shared__ __align__(16) u16 As[128 * 32];
  __shared__ __align__(16) u16 Bs[128 * 32];
  f32x4 acc[4][4] = {};
  int m0 = blockIdx.x * 128, n0 = blockIdx.y * 128;
  gemm_core(A, W, As, Bs, acc, m0, n0, C_);

  int lane = threadIdx.x & 63, wid = threadIdx.x >> 6;
  int wr = wid >> 1, wc = wid & 1;
  int rg = lane >> 4, cl = lane & 15;
#pragma unroll
  for (int n = 0; n < 4; ++n) {
    int gn = n0 + wc * 64 + n * 16 + cl;
    float bv = bias[gn];
#pragma unroll
    for (int m = 0; m < 4; ++m) {
#pragma unroll
      for (int r = 0; r < 4; ++r) {
        int gm = m0 + wr * 64 + m * 16 + rg * 4 + r;
        out[gm * 1024 + gn] = acc[m][n][r] + bv;
      }
    }
  }
}

// ---------------- flash attention v11: kv-split 2-wave blocks ----------------
// R4's proven body/mapping (bh=bid&31, qwi=63-(bid>>5), LDS P path), but each
// 32-q-row unit is a 128-thread block: wave w handles kv columns [32w,32w+32)
// of EVERY tile. K/V loads, S, exp2, P, PV all split exactly in half (no
// duplication; no-max softmax => o/l partials add exactly). Zero barriers in
// the main loop; one LDS exchange + barrier at the epilogue. 4 waves/SIMD.
__global__ __launch_bounds__(128, 2) void attn_fwd(const u16* __restrict__ Qb,
                                                   const u16* __restrict__ Kb,
                                                   const u16* __restrict__ Vt,
                                                   u16* __restrict__ Yb) {
  __shared__ __align__(16) u16 Ps[2][32 * 64];   // per-wave P tile (R4 layout)
  __shared__ __align__(16) f32x4 Co[8][64];      // wave1 o partials
  __shared__ float Cl[2][64];                    // wave1 l partials
  int tid = threadIdx.x, lane = tid & 63, wid = tid >> 6;
  int cl = lane & 15, kg = lane >> 4;
  int bid = blockIdx.x;
  int bh = bid & 31;                   // CU-local head (R4 locality)
  int qwi = 63 - (bid >> 5);           // heavy-first
  int qw0 = qwi * 32;
  int jmax = qwi >> 1;
  int fc0 = wid * 2;                   // this wave's global fc pair: fc0, fc0+1
  const u16* Qp = Qb + (size_t)bh * (2048 * 64);
  const u16* Kp = Kb + (size_t)bh * (2048 * 64);
  const u16* Vp = Vt + (size_t)bh * (64 * 2048);
  u16* Pw = Ps[wid];

  int kbase = cl * 64 + kg * 8;                 // + (fc0+fcl)*1024 + j*4096 (+32 dk)
  int vbase = cl * 2048 + wid * 32 + kg * 8;    // + dc*32768 + j*64

  // Q fragments (B-operand), full: q = qw0 + fr*16 + cl, d-slice dk*32 + kg*8
  bf16x8 qf[2][2];
#pragma unroll
  for (int fr = 0; fr < 2; ++fr)
#pragma unroll
    for (int dk = 0; dk < 2; ++dk)
      qf[fr][dk] = *(const bf16x8*)(Qp + (qw0 + fr * 16 + cl) * 64 + dk * 32 + kg * 8);

  f32x4 o[2][4] = {};
  float lsum[2] = {0.f, 0.f};
  const f32x4 CINIT = {-C8, -C8, -C8, -C8};

  for (int j = 0; j <= jmax; ++j) {
    bool edge = (j == jmax);
    int fcTop = edge ? ((qwi & 1) ? 3 : 1) : 3;
    if (fc0 > fcTop) continue;          // wave-uniform; only wave1 on even-qwi edge

    // K frags for this wave's two fc rows-of-16 (die into S-MFMA)
    bf16x8 kf[2][2];
    const u16* Kj = Kp + j * 4096 + kbase;
#pragma unroll
    for (int fcl = 0; fcl < 2; ++fcl) {
      kf[fcl][0] = *(const bf16x8*)(Kj + (fc0 + fcl) * 1024);
      kf[fcl][1] = *(const bf16x8*)(Kj + (fc0 + fcl) * 1024 + 32);
    }
    // V frags: this wave's kv half only (issue early, used after softmax)
    bf16x8 vf[4];
    const u16* Vj = Vp + j * 64 + vbase;
#pragma unroll
    for (int dc = 0; dc < 4; ++dc)
      vf[dc] = *(const bf16x8*)(Vj + dc * 32768);

    // S^T = K Q^T - C8 : lane holds q = fr*16+cl, kv = (fc0+fcl)*16 + kg*4 + r
    f32x4 s[2][2];
#pragma unroll
    for (int fcl = 0; fcl < 2; ++fcl)
#pragma unroll
      for (int fr = 0; fr < 2; ++fr) {
        f32x4 z = CINIT;
        z = __builtin_amdgcn_mfma_f32_16x16x32_bf16(kf[fcl][0], qf[fr][0], z, 0, 0, 0);
        z = __builtin_amdgcn_mfma_f32_16x16x32_bf16(kf[fcl][1], qf[fr][1], z, 0, 0, 0);
        s[fr][fcl] = z;
      }
    if (edge) {
#pragma unroll
      for (int fr = 0; fr < 2; ++fr) {
        int qg = qw0 + fr * 16 + cl;
#pragma unroll
        for (int fcl = 0; fcl < 2; ++fcl)
#pragma unroll
          for (int r = 0; r < 4; ++r)
            if (j * 64 + (fc0 + fcl) * 16 + kg * 4 + r > qg) s[fr][fcl][r] = -1e30f;
      }
    }

    // P = exp2(S); lsum; write P half-tile (R4 swizzle, global fc index)
#pragma unroll
    for (int fr = 0; fr < 2; ++fr) {
      int rowb = (fr * 16 + cl) * 64;
#pragma unroll
      for (int fcl = 0; fcl < 2; ++fcl) {
        bf16x4 pw;
#pragma unroll
        for (int r = 0; r < 4; ++r) {
          float p = exp2f(s[fr][fcl][r]);
          lsum[fr] += p;
          pw[r] = (short)f2bf(p);
        }
        int fc = fc0 + fcl;
        *(bf16x4*)(Pw + rowb + (((fc * 2 + (kg >> 1)) ^ (cl & 7)) * 8) + (kg & 1) * 4) = pw;
      }
    }
    // P A-frags (own kv half: granules wid*4+kg) + PV
#pragma unroll
    for (int fr = 0; fr < 2; ++fr) {
      int rowb = (fr * 16 + cl) * 64;
      bf16x8 pf = *(const bf16x8*)(Pw + rowb + (((wid * 4 + kg) ^ (cl & 7)) * 8));
#pragma unroll
      for (int dc = 0; dc < 4; ++dc)
        o[fr][dc] = __builtin_amdgcn_mfma_f32_16x16x32_bf16(pf, vf[dc], o[fr][dc], 0, 0, 0);
    }
  }

  // combine: wave1 publishes partials; wave0 reduces, normalizes, stores
  if (wid == 1) {
#pragma unroll
    for (int fr = 0; fr < 2; ++fr) {
      Cl[fr][lane] = lsum[fr];
#pragma unroll
      for (int dc = 0; dc < 4; ++dc) Co[fr * 4 + dc][lane] = o[fr][dc];
    }
  }
  __syncthreads();
  if (wid == 0) {
    int b = bh >> 4, h = bh & 15;
#pragma unroll
    for (int fr = 0; fr < 2; ++fr) {
      float l = lsum[fr] + Cl[fr][lane];
#pragma unroll
      for (int dc = 0; dc < 4; ++dc) o[fr][dc] += Co[fr * 4 + dc][lane];
      l += __shfl_xor(l, 16);
      l += __shfl_xor(l, 32);
      float linv = 1.f / l;
      float li[4];
#pragma unroll
      for (int r = 0; r < 4; ++r) li[r] = __shfl(linv, kg * 4 + r);
#pragma unroll
      for (int dc = 0; dc < 4; ++dc)
#pragma unroll
        for (int r = 0; r < 4; ++r) {
          int t = qw0 + fr * 16 + kg * 4 + r;
          int d = dc * 16 + cl;
          Yb[((size_t)(b * 2048 + t)) * 1024 + h * 64 + d] = f2bf(o[fr][dc][r] * li[r]);
        }
    }
  }
}

extern "C" void kernel_launch(void* const* d_in, const int* in_sizes, int n_in,
                              void* d_out, int out_size, void* d_ws, size_t ws_size,
                              hipStream_t stream) {
  const float* x  = (const float*)d_in[0];
  const float* Wa = (const float*)d_in[1];
  const float* ba = (const float*)d_in[2];
  const float* Wp = (const float*)d_in[3];
  const float* bp = (const float*)d_in[4];
  float* out = (float*)d_out;

  u16* xb  = (u16*)d_ws;
  u16* Wab = xb  + (size_t)M_ * C_;
  u16* Wpb = Wab + (size_t)N1_ * C_;
  u16* Qb  = Wpb + (size_t)C_ * C_;
  u16* Kb  = Qb  + (size_t)M_ * C_;
  u16* Vt  = Kb  + (size_t)M_ * C_;
  u16* Yb  = Vt  + (size_t)M_ * C_;

  cvt_bf16<<<(M_ * C_) / 2048, 256, 0, stream>>>(x, xb, M_ * C_);
  cvt_bf16<<<(N1_ * C_) / 2048, 256, 0, stream>>>(Wa, Wab, N1_ * C_);
  cvt_bf16<<<(C_ * C_) / 2048, 256, 0, stream>>>(Wp, Wpb, C_ * C_);
  gemm_qkv<<<dim3(M_ / 128, N1_ / 128), 256, 0, stream>>>(xb, Wab, ba, Qb, Kb, Vt);
  attn_fwd<<<2048, 128, 0, stream>>>(Qb, Kb, Vt, Yb);
  gemm_proj<<<dim3(M_ / 128, C_ / 128), 256, 0, stream>>>(Yb, Wpb, bp, out);
}

// Round 12
// 138.142 us; speedup vs baseline: 1.4093x; 1.0364x over previous
//
#include <hip/hip_runtime.h>

#define B_  2
#define T_  2048
#define C_  1024
#define H_  16
#define D_  64
#define M_  (B_*T_)   // 4096
#define N1_ (3*C_)    // 3072

typedef short bf16x8 __attribute__((ext_vector_type(8)));
typedef short bf16x4 __attribute__((ext_vector_type(4)));
typedef float f32x4 __attribute__((ext_vector_type(4)));
typedef unsigned short u16;
typedef u16 u16x8 __attribute__((ext_vector_type(8)));

#define QSCALE 0.18033688011112042f   // (1/8) * log2(e)
#define C8     11.541560327111707f    // 8 * log2(e)

__device__ __forceinline__ u16 f2bf(float f) {
  unsigned u = __float_as_uint(f);
  u += 0x7FFFu + ((u >> 16) & 1u);
  return (u16)(u >> 16);
}

__device__ __forceinline__ void gload16(const void* g, void* l) {
  __builtin_amdgcn_global_load_lds((__attribute__((address_space(1))) void*)g,
                                   (__attribute__((address_space(3))) void*)l,
                                   16, 0, 0);
}

// ---------------- fp32 -> bf16 conversion ----------------
__global__ __launch_bounds__(256) void cvt_bf16(const float* __restrict__ in,
                                                u16* __restrict__ out, int n) {
  int i = (blockIdx.x * 256 + threadIdx.x) * 8;
  if (i >= n) return;
  float4 a = *(const float4*)(in + i);
  float4 b = *(const float4*)(in + i + 4);
  u16x8 o;
  o[0] = f2bf(a.x); o[1] = f2bf(a.y); o[2] = f2bf(a.z); o[3] = f2bf(a.w);
  o[4] = f2bf(b.x); o[5] = f2bf(b.y); o[6] = f2bf(b.z); o[7] = f2bf(b.w);
  *(u16x8*)(out + i) = o;
}

// ---------------- shared GEMM mainloop: C += A[M,K] * W[N,K]^T ----------------
__device__ __forceinline__ void gemm_core(const u16* __restrict__ A,
                                          const u16* __restrict__ W,
                                          u16* As, u16* Bs,
                                          f32x4 (&acc)[4][4],
                                          int m0, int n0, int K) {
  int tid = threadIdx.x;
  int lane = tid & 63, wid = tid >> 6;
  int wr = wid >> 1, wc = wid & 1;

  int arow = wid * 16 + (lane >> 2);
  int ag = lane & 3;
  int sg = ag ^ ((arow >> 1) & 3);
  const u16* aSrc0 = A + (m0 + arow) * K + sg * 8;
  const u16* aSrc1 = aSrc0 + 64 * K;
  const u16* bSrc0 = W + (n0 + arow) * K + sg * 8;
  const u16* bSrc1 = bSrc0 + 64 * K;
  u16* aDst0 = As + (wid * 16) * 32;
  u16* aDst1 = As + (64 + wid * 16) * 32;
  u16* bDst0 = Bs + (wid * 16) * 32;
  u16* bDst1 = Bs + (64 + wid * 16) * 32;

  int rg = lane >> 4;
  int aoff[4], boff[4];
#pragma unroll
  for (int m = 0; m < 4; ++m) {
    int row = wr * 64 + m * 16 + (lane & 15);
    aoff[m] = row * 32 + (rg ^ ((row >> 1) & 3)) * 8;
    row = wc * 64 + m * 16 + (lane & 15);
    boff[m] = row * 32 + (rg ^ ((row >> 1) & 3)) * 8;
  }

  for (int kt = 0; kt < K / 32; ++kt) {
    int k0 = kt * 32;
    __syncthreads();
    gload16(aSrc0 + k0, aDst0);
    gload16(aSrc1 + k0, aDst1);
    gload16(bSrc0 + k0, bDst0);
    gload16(bSrc1 + k0, bDst1);
    __syncthreads();

    bf16x8 af[4], bfr[4];
#pragma unroll
    for (int m = 0; m < 4; ++m) af[m] = *(const bf16x8*)(As + aoff[m]);
#pragma unroll
    for (int n = 0; n < 4; ++n) bfr[n] = *(const bf16x8*)(Bs + boff[n]);
#pragma unroll
    for (int m = 0; m < 4; ++m)
#pragma unroll
      for (int n = 0; n < 4; ++n)
        acc[m][n] = __builtin_amdgcn_mfma_f32_16x16x32_bf16(af[m], bfr[n], acc[m][n], 0, 0, 0);
  }
}

// ---------------- GEMM1: qkv = x @ W_attn^T + b; Q pre-scaled by log2e/8 ----------------
__global__ __launch_bounds__(256) void gemm_qkv(const u16* __restrict__ A,
                                                const u16* __restrict__ W,
                                                const float* __restrict__ bias,
                                                u16* __restrict__ Qb,
                                                u16* __restrict__ Kb,
                                                u16* __restrict__ Vt) {
  __shared__ __align__(16) u16 As[128 * 32];
  __shared__ __align__(16) u16 Bs[128 * 32];
  f32x4 acc[4][4] = {};
  int m0 = blockIdx.x * 128, n0 = blockIdx.y * 128;
  gemm_core(A, W, As, Bs, acc, m0, n0, C_);

  int lane = threadIdx.x & 63, wid = threadIdx.x >> 6;
  int wr = wid >> 1, wc = wid & 1;
  int rg = lane >> 4, cl = lane & 15;
#pragma unroll
  for (int n = 0; n < 4; ++n) {
    int gn = n0 + wc * 64 + n * 16 + cl;
    float bv = bias[gn];
    int seg = gn >> 10, cc = gn & 1023;
    int h = cc >> 6, d = cc & 63;
    float sc = (seg == 0) ? QSCALE : 1.0f;
#pragma unroll
    for (int m = 0; m < 4; ++m) {
#pragma unroll
      for (int r = 0; r < 4; ++r) {
        int gm = m0 + wr * 64 + m * 16 + rg * 4 + r;
        int b = gm >> 11, t = gm & 2047;
        u16 val = f2bf((acc[m][n][r] + bv) * sc);
        int bh = b * 16 + h;
        if (seg == 0)      Qb[(bh * 2048 + t) * 64 + d] = val;
        else if (seg == 1) Kb[(bh * 2048 + t) * 64 + d] = val;
        else               Vt[(bh * 64 + d) * 2048 + t] = val;
      }
    }
  }
}

// ---------------- GEMM2: out = y @ W_proj^T + b (fp32 out) ----------------
__global__ __launch_bounds__(256) void gemm_proj(const u16* __restrict__ A,
                                                 const u16* __restrict__ W,
                                                 const float* __restrict__ bias,
                                                 float* __restrict__ out) {
  __shared__ __align__(16) u16 As[128 * 32];
  __shared__ __align__(16) u16 Bs[128 * 32];
  f32x4 acc[4][4] = {};
  int m0 = blockIdx.x * 128, n0 = blockIdx.y * 128;
  gemm_core(A, W, As, Bs, acc, m0, n0, C_);

  int lane = threadIdx.x & 63, wid = threadIdx.x >> 6;
  int wr = wid >> 1, wc = wid & 1;
  int rg = lane >> 4, cl = lane & 15;
#pragma unroll
  for (int n = 0; n < 4; ++n) {
    int gn = n0 + wc * 64 + n * 16 + cl;
    float bv = bias[gn];
#pragma unroll
    for (int m = 0; m < 4; ++m) {
#pragma unroll
      for (int r = 0; r < 4; ++r) {
        int gm = m0 + wr * 64 + m * 16 + rg * 4 + r;
        out[gm * 1024 + gn] = acc[m][n][r] + bv;
      }
    }
  }
}

// ---------------- flash attention v12: kv-split 2-wave + K ping-pong ----------------
// v11 body (kv-split halves per-wave chain; 4 waves/SIMD) + R4's proven K
// prefetch: next tile's K frags (16 VGPR) issue before current tile's
// compute, killing the serial ~250cy L2 load at each tile top. V stays
// single-buffered (issued early, hidden under S+softmax). Zero main-loop
// barriers; one LDS exchange at the epilogue.
__global__ __launch_bounds__(128, 2) void attn_fwd(const u16* __restrict__ Qb,
                                                   const u16* __restrict__ Kb,
                                                   const u16* __restrict__ Vt,
                                                   u16* __restrict__ Yb) {
  __shared__ __align__(16) u16 Ps[2][32 * 64];   // per-wave P tile
  __shared__ __align__(16) f32x4 Co[8][64];      // wave1 o partials
  __shared__ float Cl[2][64];                    // wave1 l partials
  int tid = threadIdx.x, lane = tid & 63, wid = tid >> 6;
  int cl = lane & 15, kg = lane >> 4;
  int bid = blockIdx.x;
  int bh = bid & 31;                   // CU-local head
  int qwi = 63 - (bid >> 5);           // heavy-first
  int qw0 = qwi * 32;
  int jmax = qwi >> 1;
  int fc0 = wid * 2;                   // this wave's fc pair
  const u16* Qp = Qb + (size_t)bh * (2048 * 64);
  const u16* Kp = Kb + (size_t)bh * (2048 * 64);
  const u16* Vp = Vt + (size_t)bh * (64 * 2048);
  u16* Pw = Ps[wid];

  int kbase = cl * 64 + kg * 8 + fc0 * 1024;    // + fcl*1024 + j*4096 (+32 dk)
  int vbase = cl * 2048 + wid * 32 + kg * 8;    // + dc*32768 + j*64

  // Q fragments (B-operand): q = qw0 + fr*16 + cl, d-slice dk*32 + kg*8
  bf16x8 qf[2][2];
#pragma unroll
  for (int fr = 0; fr < 2; ++fr)
#pragma unroll
    for (int dk = 0; dk < 2; ++dk)
      qf[fr][dk] = *(const bf16x8*)(Qp + (qw0 + fr * 16 + cl) * 64 + dk * 32 + kg * 8);

  f32x4 o[2][4] = {};
  float lsum[2] = {0.f, 0.f};
  const f32x4 CINIT = {-C8, -C8, -C8, -C8};

  auto LOADK = [&](bf16x8 (&kf)[2][2], int j) {
    const u16* Kj = Kp + j * 4096 + kbase;
#pragma unroll
    for (int fcl = 0; fcl < 2; ++fcl) {
      kf[fcl][0] = *(const bf16x8*)(Kj + fcl * 1024);
      kf[fcl][1] = *(const bf16x8*)(Kj + fcl * 1024 + 32);
    }
  };

  auto CORE = [&](bf16x8 (&kf)[2][2], int j, bool edge) {
    // V frags: own kv half, issued first (used after softmax)
    bf16x8 vf[4];
    const u16* Vj = Vp + j * 64 + vbase;
#pragma unroll
    for (int dc = 0; dc < 4; ++dc)
      vf[dc] = *(const bf16x8*)(Vj + dc * 32768);

    // S^T = K Q^T - C8 : lane holds q = fr*16+cl, kv = (fc0+fcl)*16 + kg*4 + r
    f32x4 s[2][2];
#pragma unroll
    for (int fcl = 0; fcl < 2; ++fcl)
#pragma unroll
      for (int fr = 0; fr < 2; ++fr) {
        f32x4 z = CINIT;
        z = __builtin_amdgcn_mfma_f32_16x16x32_bf16(kf[fcl][0], qf[fr][0], z, 0, 0, 0);
        z = __builtin_amdgcn_mfma_f32_16x16x32_bf16(kf[fcl][1], qf[fr][1], z, 0, 0, 0);
        s[fr][fcl] = z;
      }
    if (edge) {
#pragma unroll
      for (int fr = 0; fr < 2; ++fr) {
        int qg = qw0 + fr * 16 + cl;
#pragma unroll
        for (int fcl = 0; fcl < 2; ++fcl)
#pragma unroll
          for (int r = 0; r < 4; ++r)
            if (j * 64 + (fc0 + fcl) * 16 + kg * 4 + r > qg) s[fr][fcl][r] = -1e30f;
      }
    }

    // P = exp2(S); lsum; write P half-tile (swizzled)
#pragma unroll
    for (int fr = 0; fr < 2; ++fr) {
      int rowb = (fr * 16 + cl) * 64;
#pragma unroll
      for (int fcl = 0; fcl < 2; ++fcl) {
        bf16x4 pw;
#pragma unroll
        for (int r = 0; r < 4; ++r) {
          float p = exp2f(s[fr][fcl][r]);
          lsum[fr] += p;
          pw[r] = (short)f2bf(p);
        }
        int fc = fc0 + fcl;
        *(bf16x4*)(Pw + rowb + (((fc * 2 + (kg >> 1)) ^ (cl & 7)) * 8) + (kg & 1) * 4) = pw;
      }
    }
    // P A-frags (own kv half) + PV
#pragma unroll
    for (int fr = 0; fr < 2; ++fr) {
      int rowb = (fr * 16 + cl) * 64;
      bf16x8 pf = *(const bf16x8*)(Pw + rowb + (((wid * 4 + kg) ^ (cl & 7)) * 8));
#pragma unroll
      for (int dc = 0; dc < 4; ++dc)
        o[fr][dc] = __builtin_amdgcn_mfma_f32_16x16x32_bf16(pf, vf[dc], o[fr][dc], 0, 0, 0);
    }
  };

  bool edgeMine = (fc0 <= ((qwi & 1) ? 3 : 1));  // wave1 idle on even-qwi edge

  bf16x8 kA[2][2], kB[2][2];
  LOADK(kA, 0);
  if (jmax == 0) {
    if (edgeMine) CORE(kA, 0, true);
  } else {
    LOADK(kB, 1);
    int j = 0;
    while (j + 1 < jmax) {
      CORE(kA, j, false);
      LOADK(kA, j + 2);
      CORE(kB, j + 1, false);
      LOADK(kB, (j + 3 <= jmax) ? j + 3 : jmax);
      j += 2;
    }
    if (j < jmax) { CORE(kA, j, false); if (edgeMine) CORE(kB, jmax, true); }
    else          { if (edgeMine) CORE(kA, jmax, true); }
  }

  // combine: wave1 publishes partials; wave0 reduces, normalizes, stores
  if (wid == 1) {
#pragma unroll
    for (int fr = 0; fr < 2; ++fr) {
      Cl[fr][lane] = lsum[fr];
#pragma unroll
      for (int dc = 0; dc < 4; ++dc) Co[fr * 4 + dc][lane] = o[fr][dc];
    }
  }
  __syncthreads();
  if (wid == 0) {
    int b = bh >> 4, h = bh & 15;
#pragma unroll
    for (int fr = 0; fr < 2; ++fr) {
      float l = lsum[fr] + Cl[fr][lane];
#pragma unroll
      for (int dc = 0; dc < 4; ++dc) o[fr][dc] += Co[fr * 4 + dc][lane];
      l += __shfl_xor(l, 16);
      l += __shfl_xor(l, 32);
      float linv = 1.f / l;
      float li[4];
#pragma unroll
      for (int r = 0; r < 4; ++r) li[r] = __shfl(linv, kg * 4 + r);
#pragma unroll
      for (int dc = 0; dc < 4; ++dc)
#pragma unroll
        for (int r = 0; r < 4; ++r) {
          int t = qw0 + fr * 16 + kg * 4 + r;
          int d = dc * 16 + cl;
          Yb[((size_t)(b * 2048 + t)) * 1024 + h * 64 + d] = f2bf(o[fr][dc][r] * li[r]);
        }
    }
  }
}

extern "C" void kernel_launch(void* const* d_in, const int* in_sizes, int n_in,
                              void* d_out, int out_size, void* d_ws, size_t ws_size,
                              hipStream_t stream) {
  const float* x  = (const float*)d_in[0];
  const float* Wa = (const float*)d_in[1];
  const float* ba = (const float*)d_in[2];
  const float* Wp = (const float*)d_in[3];
  const float* bp = (const float*)d_in[4];
  float* out = (float*)d_out;

  u16* xb  = (u16*)d_ws;
  u16* Wab = xb  + (size_t)M_ * C_;
  u16* Wpb = Wab + (size_t)N1_ * C_;
  u16* Qb  = Wpb + (size_t)C_ * C_;
  u16* Kb  = Qb  + (size_t)M_ * C_;
  u16* Vt  = Kb  + (size_t)M_ * C_;
  u16* Yb  = Vt  + (size_t)M_ * C_;

  cvt_bf16<<<(M_ * C_) / 2048, 256, 0, stream>>>(x, xb, M_ * C_);
  cvt_bf16<<<(N1_ * C_) / 2048, 256, 0, stream>>>(Wa, Wab, N1_ * C_);
  cvt_bf16<<<(C_ * C_) / 2048, 256, 0, stream>>>(Wp, Wpb, C_ * C_);
  gemm_qkv<<<dim3(M_ / 128, N1_ / 128), 256, 0, stream>>>(xb, Wab, ba, Qb, Kb, Vt);
  attn_fwd<<<2048, 128, 0, stream>>>(Qb, Kb, Vt, Yb);
  gemm_proj<<<dim3(M_ / 128, C_ / 128), 256, 0, stream>>>(Yb, Wpb, bp, out);
}